// Round 7
// baseline (882.234 us; speedup 1.0000x reference)
//
#include <hip/hip_runtime.h>
#include <hip/hip_bf16.h>

typedef __hip_bfloat16 bf16;
typedef __attribute__((ext_vector_type(8))) short short8;   // 8 bf16 (4 VGPR) MFMA frag
typedef __attribute__((ext_vector_type(4))) float f32x4;    // MFMA acc

#define B_ 64
#define T_ 50
#define IMG_ 16384
#define EH_ 256
#define M_ (B_*T_)       // 3200
#define NSTEP_ 100
#define KSPLIT 4
#define KCH (IMG_/KSPLIT) // 4096

__device__ __forceinline__ float b2f(bf16 x){ return __bfloat162float(x); }
__device__ __forceinline__ bf16  f2b(float x){ return __float2bfloat16(x); }
__device__ __forceinline__ short f2bs(float x){
  bf16 h = __float2bfloat16(x);
  union { bf16 b; short s; } u; u.b = h; return u.s;
}
__device__ __forceinline__ float frcp(float x){ return __builtin_amdgcn_rcpf(x); }
__device__ __forceinline__ float ftanh(float x){
  float e = __expf(2.0f*x);              // inf-safe: e=inf -> 1, e=0 -> -1
  return 1.0f - 2.0f*frcp(e+1.0f);
}
__device__ __forceinline__ float fsigmoid(float x){ return frcp(1.0f + __expf(-x)); }
__device__ __forceinline__ float fsoftplus(float x){
  return fmaxf(x,0.0f) + log1pf(__expf(-fabsf(x)));
}

// ------- enc_w1 [16384][256] f32 -> W1T [256][16384] bf16 (W1T[h][k]=w1[k][h]) ------------
__global__ void k_transpose(const float* __restrict__ w1, bf16* __restrict__ w1T){
  __shared__ short tile[64*264];   // pad: 264 shorts keeps 8B alignment, spreads banks
  int k0 = blockIdx.x * 64;
  int tid = threadIdx.x;
  #pragma unroll
  for (int p=0;p<16;p++){            // load 64 rows x 256 cols (float4), convert to bf16
    int q = p*256 + tid;
    int row = q >> 6, c4 = q & 63;
    float4 v = *(const float4*)(w1 + (k0+row)*256 + c4*4);
    uint2 pv;
    pv.x = (unsigned int)(unsigned short)f2bs(v.x) | ((unsigned int)(unsigned short)f2bs(v.y) << 16);
    pv.y = (unsigned int)(unsigned short)f2bs(v.z) | ((unsigned int)(unsigned short)f2bs(v.w) << 16);
    *(uint2*)&tile[row*264 + c4*4] = pv;
  }
  __syncthreads();
  #pragma unroll
  for (int p=0;p<32;p++){            // write w1T[c][k0+jp*2 .. +1]
    int q = p*256 + tid;
    int c = q >> 5, jp = q & 31;
    unsigned int a = (unsigned short)tile[(jp*2)*264 + c];
    unsigned int b = (unsigned short)tile[(jp*2+1)*264 + c];
    *(unsigned int*)(w1T + c*16384 + k0 + jp*2) = a | (b<<16);
  }
}

// ------- dec_w2 [256][16384] f32 -> W2T [16384][256] bf16 (W2T[img][k]=w2[k][img]) --------
__global__ void k_transpose_w2(const float* __restrict__ w2, bf16* __restrict__ w2T){
  __shared__ short tile[256*66];     // [k][img_c], pad 66
  int img0 = blockIdx.x * 64;
  int tid = threadIdx.x;
  #pragma unroll
  for (int p=0;p<16;p++){            // load 256 k-rows x 64 img-cols (float4)
    int q = p*256 + tid;             // 0..4095
    int k = q >> 4, c4 = q & 15;
    float4 v = *(const float4*)(w2 + k*16384 + img0 + c4*4);
    tile[k*66 + c4*4 + 0] = f2bs(v.x);
    tile[k*66 + c4*4 + 1] = f2bs(v.y);
    tile[k*66 + c4*4 + 2] = f2bs(v.z);
    tile[k*66 + c4*4 + 3] = f2bs(v.w);
  }
  __syncthreads();
  #pragma unroll
  for (int p=0;p<32;p++){            // write w2T[img0+c][kp*2 .. +1]
    int q = p*256 + tid;             // 0..8191
    int c = q >> 7, kp = q & 127;
    unsigned int a = (unsigned short)tile[(kp*2)*66 + c];
    unsigned int b = (unsigned short)tile[(kp*2+1)*66 + c];
    *(unsigned int*)(w2T + (img0 + c)*256 + kp*2) = a | (b<<16);
  }
}

// ---------------- encoder GEMM: henc partial = X[3200,16384] @ W1 (split-K=4) -------------
__global__ __launch_bounds__(512) void k_enc_gemm(const float* __restrict__ X,
                                                  const bf16* __restrict__ W1T,
                                                  float* __restrict__ HP){
  __shared__ short As[2][64*64];     // [row][k] 64x64 bf16, XOR-swizzled chunks
  __shared__ short Bs[2][256*64];    // [col][k]
  int mb = blockIdx.x, ks = blockIdx.y;
  int tid = threadIdx.x;
  int l = tid & 63, w = tid >> 6;
  int wr = w >> 2, wc = w & 3;       // 2x4 wave grid over 64x256
  const int k0 = ks * KCH;
  int ar = tid >> 3, ac = tid & 7;
  const float* agp = X + (mb*64 + ar)*IMG_ + ac*8;
  int aws = ar*64 + ((ac ^ (ar&7))*8);
  f32x4 acc[2][4] = {};
  float4 areg0, areg1; uint4 breg[4];
  auto load_stage = [&](int t){
    int k = k0 + t*64;
    areg0 = *(const float4*)(agp + k);
    areg1 = *(const float4*)(agp + k + 4);
    #pragma unroll
    for (int p=0;p<4;p++){
      int q = p*512 + tid;
      int col = q>>3, c = q&7;
      breg[p] = *(const uint4*)(W1T + col*IMG_ + k + c*8);
    }
  };
  auto write_stage = [&](int buf){
    short8 s;
    s[0]=f2bs(areg0.x); s[1]=f2bs(areg0.y); s[2]=f2bs(areg0.z); s[3]=f2bs(areg0.w);
    s[4]=f2bs(areg1.x); s[5]=f2bs(areg1.y); s[6]=f2bs(areg1.z); s[7]=f2bs(areg1.w);
    *(short8*)&As[buf][aws] = s;
    #pragma unroll
    for (int p=0;p<4;p++){
      int q = p*512 + tid;
      int col = q>>3, c = q&7;
      *(uint4*)&Bs[buf][col*64 + ((c ^ (col&7))*8)] = breg[p];
    }
  };
  load_stage(0); write_stage(0);
  const int NT = KCH/64;
  for (int t=0; t<NT; t++){
    if (t+1 < NT) load_stage(t+1);   // issue-early (hide HBM under compute)
    __syncthreads();
    int buf = t & 1;
    #pragma unroll
    for (int kk=0; kk<2; kk++){
      short8 af[2], bfg[4];
      #pragma unroll
      for (int m=0;m<2;m++){
        int row = wr*32 + m*16 + (l&15);
        int ch = kk*4 + (l>>4);
        af[m] = *(const short8*)&As[buf][row*64 + ((ch ^ (row&7))*8)];
      }
      #pragma unroll
      for (int n=0;n<4;n++){
        int col = wc*64 + n*16 + (l&15);
        int ch = kk*4 + (l>>4);
        bfg[n] = *(const short8*)&Bs[buf][col*64 + ((ch ^ (col&7))*8)];
      }
      #pragma unroll
      for (int m=0;m<2;m++)
        #pragma unroll
        for (int n=0;n<4;n++)
          acc[m][n] = __builtin_amdgcn_mfma_f32_16x16x32_bf16(af[m], bfg[n], acc[m][n], 0,0,0);
    }
    __syncthreads();
    if (t+1 < NT) write_stage((t+1)&1);
  }
  float* outp = HP + ks*(M_*EH_);
  #pragma unroll
  for (int m=0;m<2;m++)
   #pragma unroll
   for (int n=0;n<4;n++)
    #pragma unroll
    for (int j=0;j<4;j++){
      int row = mb*64 + wr*32 + m*16 + (l>>4)*4 + j;
      int col = wc*64 + n*16 + (l&15);
      outp[row*EH_ + col] = acc[m][n][j];
    }
}

// ---------------- sum split-K partials + tanh + mean over T -------------------------------
__global__ void k_pool(const float* __restrict__ HP, const float* __restrict__ b1,
                       float* __restrict__ POOL){
  int b = blockIdx.x, h = threadIdx.x;
  float bias = b1[h];
  float acc = 0.f;
  for (int t=0;t<T_;t++){
    int idx = (b*T_ + t)*EH_ + h;
    float s = HP[idx] + HP[M_*EH_+idx] + HP[2*M_*EH_+idx] + HP[3*M_*EH_+idx] + bias;
    acc += ftanh(s);
  }
  POOL[b*EH_ + h] = acc * (1.0f/(float)T_);
}

// ---------------- heads + reparameterize + grounding --------------------------------------
__global__ __launch_bounds__(1024) void k_heads(const float* __restrict__ POOL,
    const float* w_mu_z0, const float* b_mu_z0, const float* w_lv_z0, const float* b_lv_z0,
    const float* w_mu_th, const float* b_mu_th, const float* w_lv_th, const float* b_lv_th,
    const float* eps_z0, const float* eps_th,
    const float* gz_w, const float* gz_b, const float* gth_w, const float* gth_b,
    float* __restrict__ out, float* __restrict__ Z0H, float* __restrict__ THH){
  __shared__ float ps[64*257];
  __shared__ float muz[1024], lvz[1024], mut[256], lvt[256];
  __shared__ float z0s[1024], ths[256];
  int tid = threadIdx.x;
  #pragma unroll
  for (int p=0;p<16;p++){
    int q = p*1024 + tid;
    ps[(q>>8)*257 + (q&255)] = POOL[q];
  }
  __syncthreads();
  {
    int b = tid>>4, k = tid&15;
    const float* pb = &ps[b*257];
    float a0=0.f, a1=0.f;
    for (int h=0; h<EH_; h++){
      float pv = pb[h];
      a0 += pv * w_mu_z0[h*16+k];
      a1 += pv * w_lv_z0[h*16+k];
    }
    a0 += b_mu_z0[k]; a1 += b_lv_z0[k];
    muz[tid]=a0; lvz[tid]=a1;
    out[52428800 + tid] = a0;   // mu_z0
    out[52429824 + tid] = a1;   // logvar_z0
  }
  if (tid < 256){
    int b = tid>>2, d = tid&3;
    const float* pb = &ps[b*257];
    float a0=0.f, a1=0.f;
    for (int h=0; h<EH_; h++){
      float pv = pb[h];
      a0 += pv * w_mu_th[h*4+d];
      a1 += pv * w_lv_th[h*4+d];
    }
    a0 += b_mu_th[d]; a1 += b_lv_th[d];
    mut[tid]=a0; lvt[tid]=a1;
    out[52430848 + tid] = a0;   // mu_theta
    out[52431104 + tid] = a1;   // logvar_theta
  }
  __syncthreads();
  z0s[tid] = muz[tid] + eps_z0[tid] * __expf(0.5f*lvz[tid]);
  if (tid<256) ths[tid] = mut[tid] + eps_th[tid] * __expf(0.5f*lvt[tid]);
  __syncthreads();
  {
    int b = tid>>4, j = tid&15;
    float a = 0.f;
    #pragma unroll
    for (int k2=0;k2<16;k2++) a += z0s[b*16+k2] * gz_w[k2*16+j];
    a += gz_b[j];
    Z0H[tid] = a;
  }
  if (tid<256){
    int b = tid>>2, j = tid&3;
    float a=0.f;
    #pragma unroll
    for (int d=0;d<4;d++) a += ths[b*4+d]*gth_w[d*4+j];
    a += gth_b[j];
    THH[tid] = fsoftplus(a);
  }
}

// ---------------- RK4 ODE: one wave per batch element -------------------------------------
__global__ __launch_bounds__(64) void k_ode(const float* __restrict__ tp,
    const float* __restrict__ act, const float* __restrict__ ow1, const float* __restrict__ ob1,
    const float* __restrict__ ow2, const float* __restrict__ ob2,
    const float* __restrict__ Z0H, const float* __restrict__ THH,
    float* __restrict__ out, float* __restrict__ ZHAT){
  __shared__ float cs[T_*128];             // theta/u/bias contribution per time-index
  __shared__ float traj[(NSTEP_+1)*16];
  __shared__ float thb[128];
  __shared__ float kb[16];
  int l = threadIdx.x;
  int b = blockIdx.x;
  float t0 = tp[0], t1 = tp[T_-1];
  float h = (t1 - t0) / 100.0f;
  float hh = 0.5f*h, h6 = h/6.0f;
  // layer-1 weight columns l and l+64 in registers
  float w1a[16], w1b[16];
  #pragma unroll
  for (int i=0;i<16;i++){ w1a[i] = ow1[i*128 + l]; w1b[i] = ow1[i*128 + 64 + l]; }
  float thv[4];
  #pragma unroll
  for (int d=0;d<4;d++) thv[d] = THH[b*4+d];
  float cA = ob1[l], cB = ob1[64+l];
  #pragma unroll
  for (int d=0;d<4;d++){
    cA += thv[d]*ow1[(16+d)*128 + l];
    cB += thv[d]*ow1[(16+d)*128 + 64 + l];
  }
  float wua0 = ow1[20*128+l],    wua1 = ow1[21*128+l];
  float wub0 = ow1[20*128+64+l], wub1 = ow1[21*128+64+l];
  for (int t=0;t<T_;t++){
    float u0 = act[(b*T_+t)*2], u1 = act[(b*T_+t)*2+1];
    cs[t*128 + l]      = cA + u0*wua0 + u1*wua1;
    cs[t*128 + 64 + l] = cB + u0*wub0 + u1*wub1;
  }
  int kq = l & 15, g = l >> 4;
  float w2g[32];                           // W2 rows g*32..g*32+31 for output kq
  #pragma unroll
  for (int jj=0;jj<32;jj++) w2g[jj] = ow2[(g*32+jj)*16 + kq];
  float b2k = ob2[kq];
  float zz[16];
  #pragma unroll
  for (int i=0;i<16;i++) zz[i] = Z0H[b*16+i];
  if (l<16) traj[l] = zz[l];
  __syncthreads();

  auto idx_of = [&](float tt)->int{
    float frac = (tt - t0) / (t1 - t0);
    int ix = (int)rintf(frac * 49.0f);     // jnp.round == half-even == rintf
    return min(max(ix,0),49);
  };
  auto feval = [&](int idx, const float* y, float* ko){
    float p1 = cs[idx*128 + l], p2 = cs[idx*128 + 64 + l];
    #pragma unroll
    for (int i=0;i<16;i++){ p1 += y[i]*w1a[i]; p2 += y[i]*w1b[i]; }
    float th1 = ftanh(p1), th2 = ftanh(p2);
    thb[l] = th1; thb[64+l] = th2;
    __syncthreads();
    float acc = 0.f;
    #pragma unroll
    for (int rr=0; rr<8; rr++){
      int r2 = (rr + g*2) & 7;             // stagger to spread LDS banks across groups
      float4 t4 = *(const float4*)&thb[g*32 + r2*4];
      acc += t4.x*w2g[r2*4+0] + t4.y*w2g[r2*4+1] + t4.z*w2g[r2*4+2] + t4.w*w2g[r2*4+3];
    }
    acc += __shfl_xor(acc, 16);
    acc += __shfl_xor(acc, 32);
    acc += b2k;
    if (l<16) kb[l] = acc;
    __syncthreads();
    #pragma unroll
    for (int i=0;i<16;i++) ko[i] = kb[i];
  };

  float y2[16], kv[16], ksum[16];
  for (int st=0; st<NSTEP_; st++){
    float tf = t0 + (float)st * h;
    int i1 = idx_of(tf), im = idx_of(tf + hh), i2 = idx_of(tf + h);
    feval(i1, zz, kv);                     // k1
    #pragma unroll
    for (int i=0;i<16;i++){ ksum[i] = kv[i]; y2[i] = zz[i] + hh*kv[i]; }
    feval(im, y2, kv);                     // k2
    #pragma unroll
    for (int i=0;i<16;i++){ ksum[i] += 2.0f*kv[i]; y2[i] = zz[i] + hh*kv[i]; }
    feval(im, y2, kv);                     // k3
    #pragma unroll
    for (int i=0;i<16;i++){ ksum[i] += 2.0f*kv[i]; y2[i] = zz[i] + h*kv[i]; }
    feval(i2, y2, kv);                     // k4
    #pragma unroll
    for (int i=0;i<16;i++){ ksum[i] += kv[i]; zz[i] = zz[i] + h6*ksum[i]; }
    if (l<16) traj[(st+1)*16 + l] = zz[l];
  }
  __syncthreads();
  if (l < T_){                             // linear interp at t_points
    float tpv = tp[l];
    float pos = (tpv - t0) / (t1 - t0) * 100.0f;
    float fi = fminf(fmaxf(floorf(pos), 0.0f), 99.0f);
    int i0 = (int)fi;
    float wv = pos - fi;
    #pragma unroll
    for (int k2=0;k2<16;k2++){
      float zv = traj[i0*16+k2]*(1.0f-wv) + traj[(i0+1)*16+k2]*wv;
      int o = (b*T_ + l)*16 + k2;
      ZHAT[o] = zv;
      out[52431360 + o] = zv;              // z_hat_seq
    }
  }
}

// ---------------- decoder layer 1: dh = tanh(zhat @ dec_w1 + b1) --------------------------
__global__ __launch_bounds__(256) void k_dh(const float* __restrict__ ZHAT,
    const float* __restrict__ dw1, const float* __restrict__ db1, bf16* __restrict__ DHB){
  __shared__ float zs[16];
  int r = blockIdx.x, hcol = threadIdx.x;
  if (hcol < 16) zs[hcol] = ZHAT[r*16 + hcol];
  __syncthreads();
  float a = db1[hcol];
  #pragma unroll
  for (int k=0;k<16;k++) a += zs[k]*dw1[k*256 + hcol];
  DHB[r*256 + hcol] = f2b(ftanh(a));
}

// ---------------- decoder GEMM: sigmoid(dh[3200,256] @ dec_w2 + b2) -----------------------
__global__ __launch_bounds__(512) void k_dec_gemm(const bf16* __restrict__ DHB,
    const bf16* __restrict__ W2T, const float* __restrict__ db2, float* __restrict__ out){
  __shared__ short As[64*256];       // full K resident
  __shared__ short Bs[2][256*64];
  int bid = blockIdx.x;
  int n = bid / 50, mb = bid % 50;   // n-major: 50 consecutive blocks share the B slab (L2)
  int tid = threadIdx.x;
  int l = tid & 63, w = tid >> 6;
  int wr = w >> 2, wc = w & 3;
  #pragma unroll
  for (int p=0;p<4;p++){
    int q = p*512 + tid;
    int r = q >> 5, c = q & 31;
    uint4 v = *(const uint4*)(DHB + (mb*64 + r)*256 + c*8);
    *(uint4*)&As[r*256 + ((c ^ (r&7))*8)] = v;
  }
  uint4 breg[4];
  auto loadB = [&](int ks){
    #pragma unroll
    for (int p=0;p<4;p++){
      int q = p*512 + tid;
      int col = q>>3, c = q&7;
      // W2T[img][k]: img = n*256+col, k = ks*64 + c*8  (stride 256 = K)
      breg[p] = *(const uint4*)(W2T + (n*256 + col)*256 + ks*64 + c*8);
    }
  };
  auto writeB = [&](int buf){
    #pragma unroll
    for (int p=0;p<4;p++){
      int q = p*512 + tid;
      int col = q>>3, c = q&7;
      *(uint4*)&Bs[buf][col*64 + ((c ^ (col&7))*8)] = breg[p];
    }
  };
  f32x4 acc[2][4] = {};
  loadB(0); writeB(0);
  for (int ks=0; ks<4; ks++){
    if (ks+1<4) loadB(ks+1);
    __syncthreads();
    #pragma unroll
    for (int kk=0;kk<2;kk++){
      short8 af[2], bfg[4];
      #pragma unroll
      for (int m=0;m<2;m++){
        int row = wr*32 + m*16 + (l&15);
        int ch = ks*8 + kk*4 + (l>>4);
        af[m] = *(const short8*)&As[row*256 + ((ch ^ (row&7))*8)];
      }
      #pragma unroll
      for (int nn=0;nn<4;nn++){
        int col = wc*64 + nn*16 + (l&15);
        int ch = kk*4 + (l>>4);
        bfg[nn] = *(const short8*)&Bs[ks&1][col*64 + ((ch ^ (col&7))*8)];
      }
      #pragma unroll
      for (int m=0;m<2;m++)
        #pragma unroll
        for (int nn=0;nn<4;nn++)
          acc[m][nn] = __builtin_amdgcn_mfma_f32_16x16x32_bf16(af[m], bfg[nn], acc[m][nn], 0,0,0);
    }
    __syncthreads();
    if (ks+1<4) writeB((ks+1)&1);
  }
  #pragma unroll
  for (int m=0;m<2;m++)
   #pragma unroll
   for (int nn=0;nn<4;nn++)
    #pragma unroll
    for (int j=0;j<4;j++){
      int row = mb*64 + wr*32 + m*16 + (l>>4)*4 + j;
      int col = n*256 + wc*64 + nn*16 + (l&15);
      float v = acc[m][nn][j] + db2[col];
      out[row*16384 + col] = fsigmoid(v);
    }
}

extern "C" void kernel_launch(void* const* d_in, const int* in_sizes, int n_in,
                              void* d_out, int out_size, void* d_ws, size_t ws_size,
                              hipStream_t stream) {
  const float* x_seq    = (const float*)d_in[0];
  const float* t_points = (const float*)d_in[1];
  const float* actions  = (const float*)d_in[2];
  const float* eps_z0   = (const float*)d_in[3];
  const float* eps_th   = (const float*)d_in[4];
  const float* enc_w1   = (const float*)d_in[5];
  const float* enc_b1   = (const float*)d_in[6];
  const float* w_mu_z0  = (const float*)d_in[7];
  const float* b_mu_z0  = (const float*)d_in[8];
  const float* w_lv_z0  = (const float*)d_in[9];
  const float* b_lv_z0  = (const float*)d_in[10];
  const float* w_mu_th  = (const float*)d_in[11];
  const float* b_mu_th  = (const float*)d_in[12];
  const float* w_lv_th  = (const float*)d_in[13];
  const float* b_lv_th  = (const float*)d_in[14];
  const float* gz_w  = (const float*)d_in[15];
  const float* gz_b  = (const float*)d_in[16];
  const float* gth_w = (const float*)d_in[17];
  const float* gth_b = (const float*)d_in[18];
  const float* ode_w1 = (const float*)d_in[19];
  const float* ode_b1 = (const float*)d_in[20];
  const float* ode_w2 = (const float*)d_in[21];
  const float* ode_b2 = (const float*)d_in[22];
  const float* dec_w1 = (const float*)d_in[23];
  const float* dec_b1 = (const float*)d_in[24];
  const float* dec_w2 = (const float*)d_in[25];
  const float* dec_b2 = (const float*)d_in[26];
  float* out = (float*)d_out;
  char* ws = (char*)d_ws;
  bf16* W1T   = (bf16*)(ws + 0);          // 8.4 MB  [256][16384]
  bf16* W2T   = (bf16*)(ws + 8388608);    // 8.4 MB  [16384][256]
  float* HP   = (float*)(ws + 16777216);  // 13.1 MB split-K partials
  float* POOL = (float*)(ws + 29884416);
  float* Z0H  = (float*)(ws + 29949952);
  float* THH  = (float*)(ws + 29954048);
  float* ZHAT = (float*)(ws + 29955072);
  bf16* DHB   = (bf16*)(ws + 30159872);

  hipLaunchKernelGGL(k_transpose,    dim3(256), dim3(256), 0, stream, enc_w1, W1T);
  hipLaunchKernelGGL(k_transpose_w2, dim3(256), dim3(256), 0, stream, dec_w2, W2T);
  hipLaunchKernelGGL(k_enc_gemm,  dim3(50,4),  dim3(512), 0, stream, x_seq, W1T, HP);
  hipLaunchKernelGGL(k_pool,      dim3(64),    dim3(256), 0, stream, HP, enc_b1, POOL);
  hipLaunchKernelGGL(k_heads,     dim3(1),     dim3(1024),0, stream, POOL,
                     w_mu_z0,b_mu_z0,w_lv_z0,b_lv_z0,w_mu_th,b_mu_th,w_lv_th,b_lv_th,
                     eps_z0, eps_th, gz_w,gz_b,gth_w,gth_b, out, Z0H, THH);
  hipLaunchKernelGGL(k_ode,       dim3(64),    dim3(64),  0, stream, t_points, actions,
                     ode_w1, ode_b1, ode_w2, ode_b2, Z0H, THH, out, ZHAT);
  hipLaunchKernelGGL(k_dh,        dim3(3200),  dim3(256), 0, stream, ZHAT, dec_w1, dec_b1, DHB);
  hipLaunchKernelGGL(k_dec_gemm,  dim3(3200),  dim3(512), 0, stream, DHB, W2T, dec_b2, out);
}